// Round 1
// baseline (559.439 us; speedup 1.0000x reference)
//
#include <hip/hip_runtime.h>
#include <hip/hip_bf16.h>

// Problem: B=2, S=2048, C=2048, H=16, D=128. All inputs fp32.
// Pipeline: cast->bf16, fused QKV GEMM (bf16 MFMA), RMSNorm+RoPE, V-transpose,
// flash attention (swapped-QK online softmax), output GEMM -> fp32.

typedef __bf16 bf16_t;
typedef __bf16 bf16x2 __attribute__((ext_vector_type(2)));
typedef __bf16 bf16x4 __attribute__((ext_vector_type(4)));
typedef __bf16 bf16x8 __attribute__((ext_vector_type(8)));
typedef float  f32x4  __attribute__((ext_vector_type(4)));

#define EPSF 1.1920928955078125e-07f
#define QSCALE 0.1275310039f   /* log2(e)/sqrt(128) folded into Q */

__device__ __forceinline__ void load_lds16(const void* g, void* l) {
  __builtin_amdgcn_global_load_lds((__attribute__((address_space(1))) void*)(g),
                                   (__attribute__((address_space(3))) void*)(l),
                                   16, 0, 0);
}

// ---------------------------------------------------------------- cast f32->bf16
__global__ __launch_bounds__(256) void castk(const float4* __restrict__ src,
                                             bf16x4* __restrict__ dst, int n4) {
  int i = blockIdx.x * blockDim.x + threadIdx.x;
  int stride = gridDim.x * blockDim.x;
  for (; i < n4; i += stride) {
    float4 v = src[i];
    bf16x4 o;
    o.x = (bf16_t)v.x; o.y = (bf16_t)v.y; o.z = (bf16_t)v.z; o.w = (bf16_t)v.w;
    dst[i] = o;
  }
}

// ---------------------------------------------------------------- GEMM C = A @ B^T
// A[M][K], B[N][K] bf16 row-major. 128x128 tile, BK=64, 256 thr (4 waves, 2x2).
// LDS XOR-swizzle (granule ^= row&7) applied via pre-swizzled global source
// (global_load_lds writes linearly) and swizzled ds_read.
// MODE 0: epilogue scatters q/k/v bf16 to [B,H,S,D] (+bias).
// MODE 1: epilogue writes fp32 out[m*N+n] (+bias0).
template <int MODE>
__global__ __launch_bounds__(256, 2)
void gemm_bt(const bf16_t* __restrict__ A, const bf16_t* __restrict__ B,
             int M, int N, int K,
             const float* __restrict__ bias0, const float* __restrict__ bias1,
             const float* __restrict__ bias2,
             float* __restrict__ outf,
             bf16_t* __restrict__ qb, bf16_t* __restrict__ kb, bf16_t* __restrict__ vb) {
  __shared__ bf16_t As[128 * 64];
  __shared__ bf16_t Bs[128 * 64];
  const int t = threadIdx.x, l = t & 63, w = t >> 6;
  const int lq = l & 15, grp = l >> 4;

  // XCD-chunked swizzle (nwg % 8 == 0 for both call sites)
  int flat = blockIdx.y * gridDim.x + blockIdx.x;
  int nwg = gridDim.x * gridDim.y;
  int cpx = nwg >> 3;
  int wg = (flat & 7) * cpx + (flat >> 3);
  int bx = wg % gridDim.x, by = wg / gridDim.x;
  const int bRow = by * 128, bCol = bx * 128;
  const int wr = w >> 1, wc = w & 1;

  // staging: lane l, chunk c covers row c*32 + w*8 + (l>>3), swizzled col granule
  const int srow = w * 8 + (l >> 3);
  const int scol = ((l & 7) ^ (l >> 3)) * 8;
  const bf16_t* Ag = A + (size_t)(bRow + srow) * K + scol;
  const bf16_t* Bg = B + (size_t)(bCol + srow) * K + scol;
  const int dstbase = w * 1024;  // bytes; HW adds lane*16

  f32x4 acc[4][4];
  const f32x4 zf = {0.f, 0.f, 0.f, 0.f};
#pragma unroll
  for (int i = 0; i < 4; ++i)
#pragma unroll
    for (int j = 0; j < 4; ++j) acc[i][j] = zf;

  const int arow = wr * 64 + lq;
  const int brow = wc * 64 + lq;
  const int axor = l & 7;

  for (int k0 = 0; k0 < K; k0 += 64) {
#pragma unroll
    for (int c = 0; c < 4; ++c)
      load_lds16(Ag + (size_t)c * 32 * K, (char*)As + c * 4096 + dstbase);
#pragma unroll
    for (int c = 0; c < 4; ++c)
      load_lds16(Bg + (size_t)c * 32 * K, (char*)Bs + c * 4096 + dstbase);
    Ag += 64; Bg += 64;
    __syncthreads();  // vmcnt(0) drain: tile visible to all waves
#pragma unroll
    for (int kk = 0; kk < 2; ++kk) {
      bf16x8 af[4], bfv[4];
#pragma unroll
      for (int i = 0; i < 4; ++i)
        af[i] = *(const bf16x8*)((const char*)As + (arow + i * 16) * 128 +
                                 (((kk << 2) + grp) ^ axor) * 16);
#pragma unroll
      for (int j = 0; j < 4; ++j)
        bfv[j] = *(const bf16x8*)((const char*)Bs + (brow + j * 16) * 128 +
                                  (((kk << 2) + grp) ^ axor) * 16);
#pragma unroll
      for (int i = 0; i < 4; ++i)
#pragma unroll
        for (int j = 0; j < 4; ++j)
          acc[i][j] = __builtin_amdgcn_mfma_f32_16x16x32_bf16(af[i], bfv[j], acc[i][j], 0, 0, 0);
    }
    __syncthreads();  // all waves done reading before next stage overwrites
  }

  if (MODE == 0) {
    const int part = bCol >> 11;            // 0=q 1=k 2=v
    const int hd_base = bCol & 2047;        // h*128 (block is 128-aligned)
    const int h = hd_base >> 7;
    const float* bias = part == 0 ? bias0 : part == 1 ? bias1 : bias2;
    bf16_t* dst = part == 0 ? qb : part == 1 ? kb : vb;
#pragma unroll
    for (int i = 0; i < 4; ++i)
#pragma unroll
      for (int j = 0; j < 4; ++j)
#pragma unroll
        for (int r = 0; r < 4; ++r) {
          int m = bRow + wr * 64 + i * 16 + grp * 4 + r;
          int d = wc * 64 + j * 16 + lq;
          int bb = m >> 11, s = m & 2047;
          float v = acc[i][j][r] + bias[hd_base + d];
          dst[(((size_t)bb * 16 + h) * 2048 + s) * 128 + d] = (bf16_t)v;
        }
  } else {
#pragma unroll
    for (int i = 0; i < 4; ++i)
#pragma unroll
      for (int j = 0; j < 4; ++j)
#pragma unroll
        for (int r = 0; r < 4; ++r) {
          int m = bRow + wr * 64 + i * 16 + grp * 4 + r;
          int n = bCol + wc * 64 + j * 16 + lq;
          outf[(size_t)m * N + n] = acc[i][j][r] + bias0[n];
        }
  }
}

// ---------------------------------------------------------------- RMSNorm + RoPE
// q,k: bf16 [B,H,S,D] in-place. One wave per 128-elem row; lane l owns pair (2l,2l+1).
// Q additionally scaled by QSCALE (softmax scale * log2e folded in).
__global__ __launch_bounds__(256)
void normrope(bf16_t* __restrict__ q, bf16_t* __restrict__ k,
              const float* __restrict__ rope,
              const float* __restrict__ gq, const float* __restrict__ gk) {
  const int l = threadIdx.x & 63, wv = threadIdx.x >> 6;
  const int rid = blockIdx.x * 4 + wv;   // row over [B,H,S]
  const int s = rid & 2047;
  const size_t base = (size_t)rid * 128 + 2 * l;
  const float4 rp = *(const float4*)(rope + ((size_t)s * 64 + l) * 4);
  const float g0q = gq[2 * l], g1q = gq[2 * l + 1];
  const float g0k = gk[2 * l], g1k = gk[2 * l + 1];

  {
    bf16x2 xq = *(const bf16x2*)(q + base);
    float x0 = (float)xq.x, x1 = (float)xq.y;
    float ss = x0 * x0 + x1 * x1;
#pragma unroll
    for (int off = 1; off < 64; off <<= 1) ss += __shfl_xor(ss, off);
    float rs = rsqrtf(ss * (1.f / 128.f) + EPSF);
    float n0 = x0 * rs * g0q, n1 = x1 * rs * g1q;
    bf16x2 o;
    o.x = (bf16_t)((rp.x * n0 + rp.y * n1) * QSCALE);
    o.y = (bf16_t)((rp.z * n0 + rp.w * n1) * QSCALE);
    *(bf16x2*)(q + base) = o;
  }
  {
    bf16x2 xk = *(const bf16x2*)(k + base);
    float x0 = (float)xk.x, x1 = (float)xk.y;
    float ss = x0 * x0 + x1 * x1;
#pragma unroll
    for (int off = 1; off < 64; off <<= 1) ss += __shfl_xor(ss, off);
    float rs = rsqrtf(ss * (1.f / 128.f) + EPSF);
    float n0 = x0 * rs * g0k, n1 = x1 * rs * g1k;
    bf16x2 o;
    o.x = (bf16_t)(rp.x * n0 + rp.y * n1);
    o.y = (bf16_t)(rp.z * n0 + rp.w * n1);
    *(bf16x2*)(k + base) = o;
  }
}

// ---------------------------------------------------------------- V transpose
// v [B,H,S,D] -> vt [B,H,D,S], 64x64 LDS tiles.
__global__ __launch_bounds__(256)
void transpose_v(const bf16_t* __restrict__ v, bf16_t* __restrict__ vt) {
  __shared__ bf16_t st[64][68];
  const int t = threadIdx.x;
  const int bh = blockIdx.z;
  const int s0 = blockIdx.x * 64, d0 = blockIdx.y * 64;
  const bf16_t* vp = v + (size_t)bh * 2048 * 128;
  bf16_t* vtp = vt + (size_t)bh * 128 * 2048;
  const int r = t >> 4, c = (t & 15) * 4;
#pragma unroll
  for (int p = 0; p < 4; ++p) {
    bf16x4 x = *(const bf16x4*)(vp + (size_t)(s0 + r + p * 16) * 128 + d0 + c);
    *(bf16x4*)&st[r + p * 16][c] = x;
  }
  __syncthreads();
#pragma unroll
  for (int p = 0; p < 4; ++p) {
    int dr = r + p * 16;
    bf16x4 y;
    y.x = st[c + 0][dr]; y.y = st[c + 1][dr]; y.z = st[c + 2][dr]; y.w = st[c + 3][dr];
    *(bf16x4*)(vtp + (size_t)(d0 + dr) * 2048 + s0 + c) = y;
  }
}

// ---------------------------------------------------------------- flash attention
// Q,K bf16 [B,H,S,D] (Q pre-scaled by QSCALE), VT bf16 [B,H,D,S].
// O bf16 [B,S,H,D]. 4 independent waves/block, 32 q-rows/wave, KV step 32.
// Swapped QK^T: lane holds S^T[kv][q=l&15]; softmax reduce = 2 shuffles.
// P goes through padded per-wave LDS [32][40] for the PV A-operand.
__global__ __launch_bounds__(256, 2)
void attn_fwd(const bf16_t* __restrict__ Q, const bf16_t* __restrict__ K,
              const bf16_t* __restrict__ VT, bf16_t* __restrict__ O) {
  __shared__ bf16_t plds[4][32 * 40];
  const int t = threadIdx.x, l = t & 63, wv = t >> 6;
  const int lq = l & 15, grp = l >> 4;
  // bh -> XCD pinning: all 16 q-blocks of a bh land on one XCD (4 bh/XCD ~ 4MB L2)
  const int bid = blockIdx.x;
  const int xcd = bid & 7, ks = bid >> 3;
  const int bh = ((ks >> 4) << 3) | xcd;
  const int qbi = ks & 15;
  const int b_ = bh >> 4, h = bh & 15;
  const bf16_t* Qp = Q + (size_t)bh * 2048 * 128;
  const bf16_t* Kp = K + (size_t)bh * 2048 * 128;
  const bf16_t* Vp = VT + (size_t)bh * 128 * 2048;
  const int q0 = qbi * 128 + wv * 32;

  bf16x8 qf[2][4];
#pragma unroll
  for (int qt = 0; qt < 2; ++qt)
#pragma unroll
    for (int c = 0; c < 4; ++c)
      qf[qt][c] = *(const bf16x8*)(Qp + (size_t)(q0 + qt * 16 + lq) * 128 + c * 32 + grp * 8);

  f32x4 o[2][8];
  const f32x4 zf = {0.f, 0.f, 0.f, 0.f};
#pragma unroll
  for (int a = 0; a < 2; ++a)
#pragma unroll
    for (int d = 0; d < 8; ++d) o[a][d] = zf;
  float m_run[2] = {-1e30f, -1e30f}, l_run[2] = {0.f, 0.f};
  bf16_t* pl = plds[wv];

  for (int kv0 = 0; kv0 < 2048; kv0 += 32) {
    f32x4 sc[2][2];
    sc[0][0] = zf; sc[0][1] = zf; sc[1][0] = zf; sc[1][1] = zf;
#pragma unroll
    for (int kvt = 0; kvt < 2; ++kvt)
#pragma unroll
      for (int c = 0; c < 4; ++c) {
        bf16x8 kf = *(const bf16x8*)(Kp + (size_t)(kv0 + kvt * 16 + lq) * 128 + c * 32 + grp * 8);
        sc[kvt][0] = __builtin_amdgcn_mfma_f32_16x16x32_bf16(kf, qf[0][c], sc[kvt][0], 0, 0, 0);
        sc[kvt][1] = __builtin_amdgcn_mfma_f32_16x16x32_bf16(kf, qf[1][c], sc[kvt][1], 0, 0, 0);
      }
#pragma unroll
    for (int qt = 0; qt < 2; ++qt) {
      float tm = fmaxf(fmaxf(fmaxf(sc[0][qt][0], sc[0][qt][1]), fmaxf(sc[0][qt][2], sc[0][qt][3])),
                       fmaxf(fmaxf(sc[1][qt][0], sc[1][qt][1]), fmaxf(sc[1][qt][2], sc[1][qt][3])));
      tm = fmaxf(tm, __shfl_xor(tm, 16));
      tm = fmaxf(tm, __shfl_xor(tm, 32));
      float mnew = fmaxf(m_run[qt], tm);
      float p0 = exp2f(sc[0][qt][0] - mnew), p1 = exp2f(sc[0][qt][1] - mnew);
      float p2 = exp2f(sc[0][qt][2] - mnew), p3 = exp2f(sc[0][qt][3] - mnew);
      float p4 = exp2f(sc[1][qt][0] - mnew), p5 = exp2f(sc[1][qt][1] - mnew);
      float p6 = exp2f(sc[1][qt][2] - mnew), p7 = exp2f(sc[1][qt][3] - mnew);
      float ts = ((p0 + p1) + (p2 + p3)) + ((p4 + p5) + (p6 + p7));
      ts += __shfl_xor(ts, 16);
      ts += __shfl_xor(ts, 32);
      float alpha = exp2f(m_run[qt] - mnew);
      m_run[qt] = mnew;
      l_run[qt] = l_run[qt] * alpha + ts;
      bf16_t* prow = pl + (qt * 16 + lq) * 40 + grp * 4;
      bf16x2 w01; w01.x = (bf16_t)p0; w01.y = (bf16_t)p1; *(bf16x2*)(prow + 0) = w01;
      bf16x2 w23; w23.x = (bf16_t)p2; w23.y = (bf16_t)p3; *(bf16x2*)(prow + 2) = w23;
      bf16x2 w45; w45.x = (bf16_t)p4; w45.y = (bf16_t)p5; *(bf16x2*)(prow + 16) = w45;
      bf16x2 w67; w67.x = (bf16_t)p6; w67.y = (bf16_t)p7; *(bf16x2*)(prow + 18) = w67;
      float ar0 = __shfl(alpha, (l & 48) | (grp * 4 + 0));
      float ar1 = __shfl(alpha, (l & 48) | (grp * 4 + 1));
      float ar2 = __shfl(alpha, (l & 48) | (grp * 4 + 2));
      float ar3 = __shfl(alpha, (l & 48) | (grp * 4 + 3));
#pragma unroll
      for (int dc = 0; dc < 8; ++dc) {
        o[qt][dc][0] *= ar0; o[qt][dc][1] *= ar1;
        o[qt][dc][2] *= ar2; o[qt][dc][3] *= ar3;
      }
    }
    bf16x8 pa0 = *(const bf16x8*)((const char*)pl + lq * 80 + grp * 16);
    bf16x8 pa1 = *(const bf16x8*)((const char*)pl + (16 + lq) * 80 + grp * 16);
#pragma unroll
    for (int dc = 0; dc < 8; ++dc) {
      bf16x8 vf = *(const bf16x8*)(Vp + (size_t)(dc * 16 + lq) * 2048 + kv0 + grp * 8);
      o[0][dc] = __builtin_amdgcn_mfma_f32_16x16x32_bf16(pa0, vf, o[0][dc], 0, 0, 0);
      o[1][dc] = __builtin_amdgcn_mfma_f32_16x16x32_bf16(pa1, vf, o[1][dc], 0, 0, 0);
    }
  }

#pragma unroll
  for (int qt = 0; qt < 2; ++qt) {
    float i0 = 1.f / __shfl(l_run[qt], (l & 48) | (grp * 4 + 0));
    float i1 = 1.f / __shfl(l_run[qt], (l & 48) | (grp * 4 + 1));
    float i2 = 1.f / __shfl(l_run[qt], (l & 48) | (grp * 4 + 2));
    float i3 = 1.f / __shfl(l_run[qt], (l & 48) | (grp * 4 + 3));
#pragma unroll
    for (int dc = 0; dc < 8; ++dc) {
      int d = dc * 16 + lq;
      int sg = q0 + qt * 16 + grp * 4;
      O[(((size_t)b_ * 2048 + sg + 0) * 16 + h) * 128 + d] = (bf16_t)(o[qt][dc][0] * i0);
      O[(((size_t)b_ * 2048 + sg + 1) * 16 + h) * 128 + d] = (bf16_t)(o[qt][dc][1] * i1);
      O[(((size_t)b_ * 2048 + sg + 2) * 16 + h) * 128 + d] = (bf16_t)(o[qt][dc][2] * i2);
      O[(((size_t)b_ * 2048 + sg + 3) * 16 + h) * 128 + d] = (bf16_t)(o[qt][dc][3] * i3);
    }
  }
}

// ---------------------------------------------------------------- launcher
extern "C" void kernel_launch(void* const* d_in, const int* in_sizes, int n_in,
                              void* d_out, int out_size, void* d_ws, size_t ws_size,
                              hipStream_t stream) {
  const float* x    = (const float*)d_in[0];
  const float* rope = (const float*)d_in[1];
  const float* Wq   = (const float*)d_in[2];
  const float* bq   = (const float*)d_in[3];
  const float* Wk   = (const float*)d_in[4];
  const float* bk   = (const float*)d_in[5];
  const float* Wv   = (const float*)d_in[6];
  const float* bv   = (const float*)d_in[7];
  const float* gq   = (const float*)d_in[8];
  const float* gk   = (const float*)d_in[9];
  const float* Wo   = (const float*)d_in[10];
  const float* bo   = (const float*)d_in[11];
  float* out = (float*)d_out;
  char* ws = (char*)d_ws;

  // workspace layout (bytes). vtb/aob reuse xbf/wqkv slots (dead after GEMM1).
  bf16_t* xbf  = (bf16_t*)(ws);                 // 16,777,216
  bf16_t* wqkv = (bf16_t*)(ws + 16777216);      // 25,165,824
  bf16_t* wobf = (bf16_t*)(ws + 41943040);      //  8,388,608
  bf16_t* qb   = (bf16_t*)(ws + 50331648);      // 16,777,216
  bf16_t* kb   = (bf16_t*)(ws + 67108864);      // 16,777,216
  bf16_t* vb   = (bf16_t*)(ws + 83886080);      // 16,777,216  (end 100,663,296)
  bf16_t* vtb  = (bf16_t*)(ws);                 // alias xbf
  bf16_t* aob  = (bf16_t*)(ws + 16777216);      // alias wqkv

  castk<<<2048, 256, 0, stream>>>((const float4*)x, (bf16x4*)xbf, 8388608 / 4);
  castk<<<1024, 256, 0, stream>>>((const float4*)Wq, (bf16x4*)wqkv, 4194304 / 4);
  castk<<<1024, 256, 0, stream>>>((const float4*)Wk, (bf16x4*)(wqkv + 4194304), 4194304 / 4);
  castk<<<1024, 256, 0, stream>>>((const float4*)Wv, (bf16x4*)(wqkv + 8388608), 4194304 / 4);
  castk<<<1024, 256, 0, stream>>>((const float4*)Wo, (bf16x4*)wobf, 4194304 / 4);

  gemm_bt<0><<<dim3(48, 32), 256, 0, stream>>>(xbf, wqkv, 4096, 6144, 2048,
                                               bq, bk, bv, nullptr, qb, kb, vb);
  normrope<<<16384, 256, 0, stream>>>(qb, kb, rope, gq, gk);
  transpose_v<<<dim3(32, 2, 32), 256, 0, stream>>>(vb, vtb);
  attn_fwd<<<512, 256, 0, stream>>>(qb, kb, vtb, aob);
  gemm_bt<1><<<dim3(16, 32), 256, 0, stream>>>(aob, wobf, 4096, 2048, 2048,
                                               bo, nullptr, nullptr, out,
                                               nullptr, nullptr, nullptr);
}

// Round 2
// 451.739 us; speedup vs baseline: 1.2384x; 1.2384x over previous
//
#include <hip/hip_runtime.h>
#include <hip/hip_bf16.h>

// Problem: B=2, S=2048, C=2048, H=16, D=128. All inputs fp32.
// Pipeline: cast->bf16, fused QKV GEMM (bf16 MFMA), RMSNorm+RoPE, V-transpose,
// flash attention (LDS-staged K/V dbuf, swapped-QK online softmax), out GEMM.

typedef __bf16 bf16_t;
typedef __bf16 bf16x2 __attribute__((ext_vector_type(2)));
typedef __bf16 bf16x4 __attribute__((ext_vector_type(4)));
typedef __bf16 bf16x8 __attribute__((ext_vector_type(8)));
typedef float  f32x4  __attribute__((ext_vector_type(4)));

#define EPSF 1.1920928955078125e-07f
#define QSCALE 0.1275310039f   /* log2(e)/sqrt(128) folded into Q */

__device__ __forceinline__ void load_lds16(const void* g, void* l) {
  __builtin_amdgcn_global_load_lds((__attribute__((address_space(1))) void*)(g),
                                   (__attribute__((address_space(3))) void*)(l),
                                   16, 0, 0);
}

// ---------------------------------------------------------------- cast f32->bf16
__global__ __launch_bounds__(256) void castk(const float4* __restrict__ src,
                                             bf16x4* __restrict__ dst, int n4) {
  int i = blockIdx.x * blockDim.x + threadIdx.x;
  int stride = gridDim.x * blockDim.x;
  for (; i < n4; i += stride) {
    float4 v = src[i];
    bf16x4 o;
    o.x = (bf16_t)v.x; o.y = (bf16_t)v.y; o.z = (bf16_t)v.z; o.w = (bf16_t)v.w;
    dst[i] = o;
  }
}

// ---------------------------------------------------------------- GEMM C = A @ B^T
template <int MODE>
__global__ __launch_bounds__(256, 2)
void gemm_bt(const bf16_t* __restrict__ A, const bf16_t* __restrict__ B,
             int M, int N, int K,
             const float* __restrict__ bias0, const float* __restrict__ bias1,
             const float* __restrict__ bias2,
             float* __restrict__ outf,
             bf16_t* __restrict__ qb, bf16_t* __restrict__ kb, bf16_t* __restrict__ vb) {
  __shared__ bf16_t As[128 * 64];
  __shared__ bf16_t Bs[128 * 64];
  const int t = threadIdx.x, l = t & 63, w = t >> 6;
  const int lq = l & 15, grp = l >> 4;

  int flat = blockIdx.y * gridDim.x + blockIdx.x;
  int nwg = gridDim.x * gridDim.y;
  int cpx = nwg >> 3;
  int wg = (flat & 7) * cpx + (flat >> 3);
  int bx = wg % gridDim.x, by = wg / gridDim.x;
  const int bRow = by * 128, bCol = bx * 128;
  const int wr = w >> 1, wc = w & 1;

  const int srow = w * 8 + (l >> 3);
  const int scol = ((l & 7) ^ (l >> 3)) * 8;
  const bf16_t* Ag = A + (size_t)(bRow + srow) * K + scol;
  const bf16_t* Bg = B + (size_t)(bCol + srow) * K + scol;
  const int dstbase = w * 1024;

  f32x4 acc[4][4];
  const f32x4 zf = {0.f, 0.f, 0.f, 0.f};
#pragma unroll
  for (int i = 0; i < 4; ++i)
#pragma unroll
    for (int j = 0; j < 4; ++j) acc[i][j] = zf;

  const int arow = wr * 64 + lq;
  const int brow = wc * 64 + lq;
  const int axor = l & 7;

  for (int k0 = 0; k0 < K; k0 += 64) {
#pragma unroll
    for (int c = 0; c < 4; ++c)
      load_lds16(Ag + (size_t)c * 32 * K, (char*)As + c * 4096 + dstbase);
#pragma unroll
    for (int c = 0; c < 4; ++c)
      load_lds16(Bg + (size_t)c * 32 * K, (char*)Bs + c * 4096 + dstbase);
    Ag += 64; Bg += 64;
    __syncthreads();
#pragma unroll
    for (int kk = 0; kk < 2; ++kk) {
      bf16x8 af[4], bfv[4];
#pragma unroll
      for (int i = 0; i < 4; ++i)
        af[i] = *(const bf16x8*)((const char*)As + (arow + i * 16) * 128 +
                                 (((kk << 2) + grp) ^ axor) * 16);
#pragma unroll
      for (int j = 0; j < 4; ++j)
        bfv[j] = *(const bf16x8*)((const char*)Bs + (brow + j * 16) * 128 +
                                  (((kk << 2) + grp) ^ axor) * 16);
#pragma unroll
      for (int i = 0; i < 4; ++i)
#pragma unroll
        for (int j = 0; j < 4; ++j)
          acc[i][j] = __builtin_amdgcn_mfma_f32_16x16x32_bf16(af[i], bfv[j], acc[i][j], 0, 0, 0);
    }
    __syncthreads();
  }

  if (MODE == 0) {
    const int part = bCol >> 11;
    const int hd_base = bCol & 2047;
    const int h = hd_base >> 7;
    const float* bias = part == 0 ? bias0 : part == 1 ? bias1 : bias2;
    bf16_t* dst = part == 0 ? qb : part == 1 ? kb : vb;
#pragma unroll
    for (int i = 0; i < 4; ++i)
#pragma unroll
      for (int j = 0; j < 4; ++j)
#pragma unroll
        for (int r = 0; r < 4; ++r) {
          int m = bRow + wr * 64 + i * 16 + grp * 4 + r;
          int d = wc * 64 + j * 16 + lq;
          int bb = m >> 11, s = m & 2047;
          float v = acc[i][j][r] + bias[hd_base + d];
          dst[(((size_t)bb * 16 + h) * 2048 + s) * 128 + d] = (bf16_t)v;
        }
  } else {
#pragma unroll
    for (int i = 0; i < 4; ++i)
#pragma unroll
      for (int j = 0; j < 4; ++j)
#pragma unroll
        for (int r = 0; r < 4; ++r) {
          int m = bRow + wr * 64 + i * 16 + grp * 4 + r;
          int n = bCol + wc * 64 + j * 16 + lq;
          outf[(size_t)m * N + n] = acc[i][j][r] + bias0[n];
        }
  }
}

// ---------------------------------------------------------------- RMSNorm + RoPE
__global__ __launch_bounds__(256)
void normrope(bf16_t* __restrict__ q, bf16_t* __restrict__ k,
              const float* __restrict__ rope,
              const float* __restrict__ gq, const float* __restrict__ gk) {
  const int l = threadIdx.x & 63, wv = threadIdx.x >> 6;
  const int rid = blockIdx.x * 4 + wv;
  const int s = rid & 2047;
  const size_t base = (size_t)rid * 128 + 2 * l;
  const float4 rp = *(const float4*)(rope + ((size_t)s * 64 + l) * 4);
  const float g0q = gq[2 * l], g1q = gq[2 * l + 1];
  const float g0k = gk[2 * l], g1k = gk[2 * l + 1];

  {
    bf16x2 xq = *(const bf16x2*)(q + base);
    float x0 = (float)xq.x, x1 = (float)xq.y;
    float ss = x0 * x0 + x1 * x1;
#pragma unroll
    for (int off = 1; off < 64; off <<= 1) ss += __shfl_xor(ss, off);
    float rs = rsqrtf(ss * (1.f / 128.f) + EPSF);
    float n0 = x0 * rs * g0q, n1 = x1 * rs * g1q;
    bf16x2 o;
    o.x = (bf16_t)((rp.x * n0 + rp.y * n1) * QSCALE);
    o.y = (bf16_t)((rp.z * n0 + rp.w * n1) * QSCALE);
    *(bf16x2*)(q + base) = o;
  }
  {
    bf16x2 xk = *(const bf16x2*)(k + base);
    float x0 = (float)xk.x, x1 = (float)xk.y;
    float ss = x0 * x0 + x1 * x1;
#pragma unroll
    for (int off = 1; off < 64; off <<= 1) ss += __shfl_xor(ss, off);
    float rs = rsqrtf(ss * (1.f / 128.f) + EPSF);
    float n0 = x0 * rs * g0k, n1 = x1 * rs * g1k;
    bf16x2 o;
    o.x = (bf16_t)(rp.x * n0 + rp.y * n1);
    o.y = (bf16_t)(rp.z * n0 + rp.w * n1);
    *(bf16x2*)(k + base) = o;
  }
}

// ---------------------------------------------------------------- V transpose
__global__ __launch_bounds__(256)
void transpose_v(const bf16_t* __restrict__ v, bf16_t* __restrict__ vt) {
  __shared__ bf16_t st[64][68];
  const int t = threadIdx.x;
  const int bh = blockIdx.z;
  const int s0 = blockIdx.x * 64, d0 = blockIdx.y * 64;
  const bf16_t* vp = v + (size_t)bh * 2048 * 128;
  bf16_t* vtp = vt + (size_t)bh * 128 * 2048;
  const int r = t >> 4, c = (t & 15) * 4;
#pragma unroll
  for (int p = 0; p < 4; ++p) {
    bf16x4 x = *(const bf16x4*)(vp + (size_t)(s0 + r + p * 16) * 128 + d0 + c);
    *(bf16x4*)&st[r + p * 16][c] = x;
  }
  __syncthreads();
#pragma unroll
  for (int p = 0; p < 4; ++p) {
    int dr = r + p * 16;
    bf16x4 y;
    y.x = st[c + 0][dr]; y.y = st[c + 1][dr]; y.z = st[c + 2][dr]; y.w = st[c + 3][dr];
    *(bf16x4*)(vtp + (size_t)(d0 + dr) * 2048 + s0 + c) = y;
  }
}

// ---------------------------------------------------------------- flash attention
// LDS-staged K/V (KVBLK=64, double-buffered via global_load_lds w16, row&7
// granule-XOR swizzle applied on the pre-swizzled global source + ds_read).
// 4 waves/block, 32 q-rows/wave (2 qt of 16). Swapped QK^T; P via per-wave
// swizzled LDS [32][64]. LDS: 64KB tiles + 16KB P = 80KB -> 2 blocks/CU.
__global__ __launch_bounds__(256, 2)
void attn_fwd(const bf16_t* __restrict__ Q, const bf16_t* __restrict__ K,
              const bf16_t* __restrict__ VT, bf16_t* __restrict__ O) {
  __shared__ char smem[81920];  // K0,K1 @0/16384; V0,V1 @32768/49152; P @65536
  const int t = threadIdx.x, l = t & 63, wv = t >> 6;
  const int lq = l & 15, grp = l >> 4;
  const int bid = blockIdx.x;
  const int xcd = bid & 7, ksid = bid >> 3;
  const int bh = ((ksid >> 4) << 3) | xcd;   // 4 bh per XCD -> K/V fits L2
  const int qbi = ksid & 15;
  const int b_ = bh >> 4, h = bh & 15;
  const bf16_t* Qp = Q + (size_t)bh * 2048 * 128;
  const bf16_t* Kp = K + (size_t)bh * 2048 * 128;
  const bf16_t* Vp = VT + (size_t)bh * 128 * 2048;
  const int q0 = qbi * 128 + wv * 32;
  const int axor = lq & 7;

  // staging source/dest offsets (4 global_load_lds per tile per thread)
  int ksoff[4], vsoff[4], dstoff[4];
#pragma unroll
  for (int i = 0; i < 4; ++i) {
    int g = (i * 4 + wv) * 64 + l;
    int kr = g >> 4, kc = g & 15;              // K tile: 64 rows x 16 granules
    ksoff[i] = kr * 256 + ((kc ^ (kr & 7)) << 4);
    int vr = g >> 3, vc = g & 7;               // V tile: 128 rows x 8 granules
    vsoff[i] = vr * 4096 + ((vc ^ (vr & 7)) << 4);
    dstoff[i] = (i * 4 + wv) * 1024;
  }

  bf16x8 qf[2][4];
#pragma unroll
  for (int qt = 0; qt < 2; ++qt)
#pragma unroll
    for (int c = 0; c < 4; ++c)
      qf[qt][c] = *(const bf16x8*)(Qp + (size_t)(q0 + qt * 16 + lq) * 128 + c * 32 + grp * 8);

  f32x4 o[2][8];
  const f32x4 zf = {0.f, 0.f, 0.f, 0.f};
#pragma unroll
  for (int a = 0; a < 2; ++a)
#pragma unroll
    for (int d = 0; d < 8; ++d) o[a][d] = zf;
  float m_run[2] = {-1e30f, -1e30f}, l_run[2] = {0.f, 0.f};
  char* pb = smem + 65536 + wv * 4096;

  auto stage = [&](int buf, int kvb) {
    char* kdst = smem + buf * 16384;
    char* vdst = smem + 32768 + buf * 16384;
    const char* ksrc = (const char*)Kp + (size_t)kvb * 256;
    const char* vsrc = (const char*)Vp + (size_t)kvb * 2;
#pragma unroll
    for (int i = 0; i < 4; ++i) load_lds16(ksrc + ksoff[i], kdst + dstoff[i]);
#pragma unroll
    for (int i = 0; i < 4; ++i) load_lds16(vsrc + vsoff[i], vdst + dstoff[i]);
  };

  stage(0, 0);
  __syncthreads();

  for (int it = 0; it < 32; ++it) {
    const int cur = it & 1;
    if (it < 31) stage(cur ^ 1, (it + 1) * 64);
    const char* kb = smem + cur * 16384;
    const char* vb = smem + 32768 + cur * 16384;

    // ---- QK^T: sc[kvt][qt], lane holds S^T[kv=kvt*16+grp*4+r][q=lq]
    f32x4 sc[4][2];
#pragma unroll
    for (int kvt = 0; kvt < 4; ++kvt) { sc[kvt][0] = zf; sc[kvt][1] = zf; }
    __builtin_amdgcn_s_setprio(1);
#pragma unroll
    for (int kvt = 0; kvt < 4; ++kvt)
#pragma unroll
      for (int c = 0; c < 4; ++c) {
        bf16x8 kf = *(const bf16x8*)(kb + (kvt * 16 + lq) * 256 +
                                     ((((c << 2) + grp) ^ axor) << 4));
        sc[kvt][0] = __builtin_amdgcn_mfma_f32_16x16x32_bf16(kf, qf[0][c], sc[kvt][0], 0, 0, 0);
        sc[kvt][1] = __builtin_amdgcn_mfma_f32_16x16x32_bf16(kf, qf[1][c], sc[kvt][1], 0, 0, 0);
      }
    __builtin_amdgcn_s_setprio(0);

    // ---- online softmax per qt (scores already in log2 domain)
#pragma unroll
    for (int qt = 0; qt < 2; ++qt) {
      float tm = sc[0][qt][0];
#pragma unroll
      for (int kvt = 0; kvt < 4; ++kvt)
#pragma unroll
        for (int r = 0; r < 4; ++r) tm = fmaxf(tm, sc[kvt][qt][r]);
      tm = fmaxf(tm, __shfl_xor(tm, 16));
      tm = fmaxf(tm, __shfl_xor(tm, 32));
      float mnew = fmaxf(m_run[qt], tm);
      float ts = 0.f;
      const int prow = (qt * 16 + lq) * 128;
#pragma unroll
      for (int kvt = 0; kvt < 4; ++kvt) {
        float p0 = exp2f(sc[kvt][qt][0] - mnew);
        float p1 = exp2f(sc[kvt][qt][1] - mnew);
        float p2 = exp2f(sc[kvt][qt][2] - mnew);
        float p3 = exp2f(sc[kvt][qt][3] - mnew);
        ts += (p0 + p1) + (p2 + p3);
        bf16x4 w;
        w.x = (bf16_t)p0; w.y = (bf16_t)p1; w.z = (bf16_t)p2; w.w = (bf16_t)p3;
        // P[q][kv]: granule (kvt*2 + grp>>1) ^ (q&7), byte (grp&1)*8
        *(bf16x4*)(pb + prow + ((((kvt << 1) | (grp >> 1)) ^ axor) << 4) +
                   ((grp & 1) << 3)) = w;
      }
      ts += __shfl_xor(ts, 16);
      ts += __shfl_xor(ts, 32);
      float alpha = exp2f(m_run[qt] - mnew);
      m_run[qt] = mnew;
      l_run[qt] = l_run[qt] * alpha + ts;
      float ar0 = __shfl(alpha, (l & 48) | (grp * 4 + 0));
      float ar1 = __shfl(alpha, (l & 48) | (grp * 4 + 1));
      float ar2 = __shfl(alpha, (l & 48) | (grp * 4 + 2));
      float ar3 = __shfl(alpha, (l & 48) | (grp * 4 + 3));
#pragma unroll
      for (int dc = 0; dc < 8; ++dc) {
        o[qt][dc][0] *= ar0; o[qt][dc][1] *= ar1;
        o[qt][dc][2] *= ar2; o[qt][dc][3] *= ar3;
      }
    }

    // ---- PV
    bf16x8 pa[2][2];
#pragma unroll
    for (int qt = 0; qt < 2; ++qt)
#pragma unroll
      for (int ks = 0; ks < 2; ++ks)
        pa[qt][ks] = *(const bf16x8*)(pb + (qt * 16 + lq) * 128 +
                                      ((((ks << 2) | grp) ^ axor) << 4));
    __builtin_amdgcn_s_setprio(1);
#pragma unroll
    for (int dc = 0; dc < 8; ++dc)
#pragma unroll
      for (int ks = 0; ks < 2; ++ks) {
        bf16x8 vf = *(const bf16x8*)(vb + (dc * 16 + lq) * 128 +
                                     ((((ks << 2) + grp) ^ axor) << 4));
        o[0][dc] = __builtin_amdgcn_mfma_f32_16x16x32_bf16(pa[0][ks], vf, o[0][dc], 0, 0, 0);
        o[1][dc] = __builtin_amdgcn_mfma_f32_16x16x32_bf16(pa[1][ks], vf, o[1][dc], 0, 0, 0);
      }
    __builtin_amdgcn_s_setprio(0);
    __syncthreads();   // stage(it+1) complete + all waves done with buf[cur]
  }

#pragma unroll
  for (int qt = 0; qt < 2; ++qt) {
    float i0 = 1.f / __shfl(l_run[qt], (l & 48) | (grp * 4 + 0));
    float i1 = 1.f / __shfl(l_run[qt], (l & 48) | (grp * 4 + 1));
    float i2 = 1.f / __shfl(l_run[qt], (l & 48) | (grp * 4 + 2));
    float i3 = 1.f / __shfl(l_run[qt], (l & 48) | (grp * 4 + 3));
#pragma unroll
    for (int dc = 0; dc < 8; ++dc) {
      int d = dc * 16 + lq;
      int sg = q0 + qt * 16 + grp * 4;
      O[(((size_t)b_ * 2048 + sg + 0) * 16 + h) * 128 + d] = (bf16_t)(o[qt][dc][0] * i0);
      O[(((size_t)b_ * 2048 + sg + 1) * 16 + h) * 128 + d] = (bf16_t)(o[qt][dc][1] * i1);
      O[(((size_t)b_ * 2048 + sg + 2) * 16 + h) * 128 + d] = (bf16_t)(o[qt][dc][2] * i2);
      O[(((size_t)b_ * 2048 + sg + 3) * 16 + h) * 128 + d] = (bf16_t)(o[qt][dc][3] * i3);
    }
  }
}

// ---------------------------------------------------------------- launcher
extern "C" void kernel_launch(void* const* d_in, const int* in_sizes, int n_in,
                              void* d_out, int out_size, void* d_ws, size_t ws_size,
                              hipStream_t stream) {
  const float* x    = (const float*)d_in[0];
  const float* rope = (const float*)d_in[1];
  const float* Wq   = (const float*)d_in[2];
  const float* bq   = (const float*)d_in[3];
  const float* Wk   = (const float*)d_in[4];
  const float* bk   = (const float*)d_in[5];
  const float* Wv   = (const float*)d_in[6];
  const float* bv   = (const float*)d_in[7];
  const float* gq   = (const float*)d_in[8];
  const float* gk   = (const float*)d_in[9];
  const float* Wo   = (const float*)d_in[10];
  const float* bo   = (const float*)d_in[11];
  float* out = (float*)d_out;
  char* ws = (char*)d_ws;

  bf16_t* xbf  = (bf16_t*)(ws);
  bf16_t* wqkv = (bf16_t*)(ws + 16777216);
  bf16_t* wobf = (bf16_t*)(ws + 41943040);
  bf16_t* qb   = (bf16_t*)(ws + 50331648);
  bf16_t* kb   = (bf16_t*)(ws + 67108864);
  bf16_t* vb   = (bf16_t*)(ws + 83886080);
  bf16_t* vtb  = (bf16_t*)(ws);              // alias xbf (dead after GEMM1)
  bf16_t* aob  = (bf16_t*)(ws + 16777216);   // alias wqkv

  castk<<<2048, 256, 0, stream>>>((const float4*)x, (bf16x4*)xbf, 8388608 / 4);
  castk<<<1024, 256, 0, stream>>>((const float4*)Wq, (bf16x4*)wqkv, 4194304 / 4);
  castk<<<1024, 256, 0, stream>>>((const float4*)Wk, (bf16x4*)(wqkv + 4194304), 4194304 / 4);
  castk<<<1024, 256, 0, stream>>>((const float4*)Wv, (bf16x4*)(wqkv + 8388608), 4194304 / 4);
  castk<<<1024, 256, 0, stream>>>((const float4*)Wo, (bf16x4*)wobf, 4194304 / 4);

  gemm_bt<0><<<dim3(48, 32), 256, 0, stream>>>(xbf, wqkv, 4096, 6144, 2048,
                                               bq, bk, bv, nullptr, qb, kb, vb);
  normrope<<<16384, 256, 0, stream>>>(qb, kb, rope, gq, gk);
  transpose_v<<<dim3(32, 2, 32), 256, 0, stream>>>(vb, vtb);
  attn_fwd<<<512, 256, 0, stream>>>(qb, kb, vtb, aob);
  gemm_bt<1><<<dim3(16, 32), 256, 0, stream>>>(aob, wobf, 4096, 2048, 2048,
                                               bo, nullptr, nullptr, out,
                                               nullptr, nullptr, nullptr);
}

// Round 4
// 424.169 us; speedup vs baseline: 1.3189x; 1.0650x over previous
//
#include <hip/hip_runtime.h>
#include <hip/hip_bf16.h>

// Problem: B=2, S=2048, C=2048, H=16, D=128. All inputs fp32.
// Pipeline: fused cast->bf16, fused QKV GEMM (bf16 MFMA), RMSNorm+RoPE,
// V-transpose, flash attention (8 waves/block, LDS K/V dbuf, in-register P via
// permlane swaps, defer-rescale), out GEMM.

typedef __bf16 bf16_t;
typedef __bf16 bf16x2 __attribute__((ext_vector_type(2)));
typedef __bf16 bf16x4 __attribute__((ext_vector_type(4)));
typedef __bf16 bf16x8 __attribute__((ext_vector_type(8)));
typedef float  f32x4  __attribute__((ext_vector_type(4)));

#define EPSF 1.1920928955078125e-07f
#define QSCALE 0.1275310039f   /* log2(e)/sqrt(128) folded into Q */

__device__ __forceinline__ void load_lds16(const void* g, void* l) {
  __builtin_amdgcn_global_load_lds((__attribute__((address_space(1))) void*)(g),
                                   (__attribute__((address_space(3))) void*)(l),
                                   16, 0, 0);
}

// ---------------------------------------------------------------- fused cast
// x (2097152 float4) -> xbf ; Wq/Wk/Wv (1048576 each) -> wqkv ; Wo -> wobf
__global__ __launch_bounds__(256)
void cast_all(const float4* __restrict__ x, const float4* __restrict__ wq,
              const float4* __restrict__ wk, const float4* __restrict__ wv,
              const float4* __restrict__ wo,
              bf16x4* __restrict__ xd, bf16x4* __restrict__ wqkvd,
              bf16x4* __restrict__ wod) {
  int i = blockIdx.x * blockDim.x + threadIdx.x;
  int stride = gridDim.x * blockDim.x;
  for (; i < 6291456; i += stride) {
    float4 v;
    bf16x4* dst;
    if (i < 2097152) {
      v = x[i]; dst = xd + i;
    } else {
      int j = i - 2097152;
      int part = j >> 20, off = j & 1048575;
      v = (part == 0 ? wq : part == 1 ? wk : part == 2 ? wv : wo)[off];
      dst = part < 3 ? (wqkvd + (part << 20) + off) : (wod + off);
    }
    bf16x4 o;
    o.x = (bf16_t)v.x; o.y = (bf16_t)v.y; o.z = (bf16_t)v.z; o.w = (bf16_t)v.w;
    *dst = o;
  }
}

// ---------------------------------------------------------------- GEMM C = A @ B^T
template <int MODE>
__global__ __launch_bounds__(256, 2)
void gemm_bt(const bf16_t* __restrict__ A, const bf16_t* __restrict__ B,
             int M, int N, int K,
             const float* __restrict__ bias0, const float* __restrict__ bias1,
             const float* __restrict__ bias2,
             float* __restrict__ outf,
             bf16_t* __restrict__ qb, bf16_t* __restrict__ kb, bf16_t* __restrict__ vb) {
  __shared__ bf16_t As[128 * 64];
  __shared__ bf16_t Bs[128 * 64];
  const int t = threadIdx.x, l = t & 63, w = t >> 6;
  const int lq = l & 15, grp = l >> 4;

  int flat = blockIdx.y * gridDim.x + blockIdx.x;
  int nwg = gridDim.x * gridDim.y;
  int cpx = nwg >> 3;
  int wg = (flat & 7) * cpx + (flat >> 3);
  int bx = wg % gridDim.x, by = wg / gridDim.x;
  const int bRow = by * 128, bCol = bx * 128;
  const int wr = w >> 1, wc = w & 1;

  const int srow = w * 8 + (l >> 3);
  const int scol = ((l & 7) ^ (l >> 3)) * 8;
  const bf16_t* Ag = A + (size_t)(bRow + srow) * K + scol;
  const bf16_t* Bg = B + (size_t)(bCol + srow) * K + scol;
  const int dstbase = w * 1024;

  f32x4 acc[4][4];
  const f32x4 zf = {0.f, 0.f, 0.f, 0.f};
#pragma unroll
  for (int i = 0; i < 4; ++i)
#pragma unroll
    for (int j = 0; j < 4; ++j) acc[i][j] = zf;

  const int arow = wr * 64 + lq;
  const int brow = wc * 64 + lq;
  const int axor = l & 7;

  for (int k0 = 0; k0 < K; k0 += 64) {
#pragma unroll
    for (int c = 0; c < 4; ++c)
      load_lds16(Ag + (size_t)c * 32 * K, (char*)As + c * 4096 + dstbase);
#pragma unroll
    for (int c = 0; c < 4; ++c)
      load_lds16(Bg + (size_t)c * 32 * K, (char*)Bs + c * 4096 + dstbase);
    Ag += 64; Bg += 64;
    __syncthreads();
#pragma unroll
    for (int kk = 0; kk < 2; ++kk) {
      bf16x8 af[4], bfv[4];
#pragma unroll
      for (int i = 0; i < 4; ++i)
        af[i] = *(const bf16x8*)((const char*)As + (arow + i * 16) * 128 +
                                 (((kk << 2) + grp) ^ axor) * 16);
#pragma unroll
      for (int j = 0; j < 4; ++j)
        bfv[j] = *(const bf16x8*)((const char*)Bs + (brow + j * 16) * 128 +
                                  (((kk << 2) + grp) ^ axor) * 16);
#pragma unroll
      for (int i = 0; i < 4; ++i)
#pragma unroll
        for (int j = 0; j < 4; ++j)
          acc[i][j] = __builtin_amdgcn_mfma_f32_16x16x32_bf16(af[i], bfv[j], acc[i][j], 0, 0, 0);
    }
    __syncthreads();
  }

  if (MODE == 0) {
    const int part = bCol >> 11;
    const int hd_base = bCol & 2047;
    const int h = hd_base >> 7;
    const float* bias = part == 0 ? bias0 : part == 1 ? bias1 : bias2;
    bf16_t* dst = part == 0 ? qb : part == 1 ? kb : vb;
#pragma unroll
    for (int i = 0; i < 4; ++i)
#pragma unroll
      for (int j = 0; j < 4; ++j)
#pragma unroll
        for (int r = 0; r < 4; ++r) {
          int m = bRow + wr * 64 + i * 16 + grp * 4 + r;
          int d = wc * 64 + j * 16 + lq;
          int bb = m >> 11, s = m & 2047;
          float v = acc[i][j][r] + bias[hd_base + d];
          dst[(((size_t)bb * 16 + h) * 2048 + s) * 128 + d] = (bf16_t)v;
        }
  } else {
#pragma unroll
    for (int i = 0; i < 4; ++i)
#pragma unroll
      for (int j = 0; j < 4; ++j)
#pragma unroll
        for (int r = 0; r < 4; ++r) {
          int m = bRow + wr * 64 + i * 16 + grp * 4 + r;
          int n = bCol + wc * 64 + j * 16 + lq;
          outf[(size_t)m * N + n] = acc[i][j][r] + bias0[n];
        }
  }
}

// ---------------------------------------------------------------- RMSNorm + RoPE
__global__ __launch_bounds__(256)
void normrope(bf16_t* __restrict__ q, bf16_t* __restrict__ k,
              const float* __restrict__ rope,
              const float* __restrict__ gq, const float* __restrict__ gk) {
  const int l = threadIdx.x & 63, wv = threadIdx.x >> 6;
  const int rid = blockIdx.x * 4 + wv;
  const int s = rid & 2047;
  const size_t base = (size_t)rid * 128 + 2 * l;
  const float4 rp = *(const float4*)(rope + ((size_t)s * 64 + l) * 4);
  const float g0q = gq[2 * l], g1q = gq[2 * l + 1];
  const float g0k = gk[2 * l], g1k = gk[2 * l + 1];

  {
    bf16x2 xq = *(const bf16x2*)(q + base);
    float x0 = (float)xq.x, x1 = (float)xq.y;
    float ss = x0 * x0 + x1 * x1;
#pragma unroll
    for (int off = 1; off < 64; off <<= 1) ss += __shfl_xor(ss, off);
    float rs = rsqrtf(ss * (1.f / 128.f) + EPSF);
    float n0 = x0 * rs * g0q, n1 = x1 * rs * g1q;
    bf16x2 o;
    o.x = (bf16_t)((rp.x * n0 + rp.y * n1) * QSCALE);
    o.y = (bf16_t)((rp.z * n0 + rp.w * n1) * QSCALE);
    *(bf16x2*)(q + base) = o;
  }
  {
    bf16x2 xk = *(const bf16x2*)(k + base);
    float x0 = (float)xk.x, x1 = (float)xk.y;
    float ss = x0 * x0 + x1 * x1;
#pragma unroll
    for (int off = 1; off < 64; off <<= 1) ss += __shfl_xor(ss, off);
    float rs = rsqrtf(ss * (1.f / 128.f) + EPSF);
    float n0 = x0 * rs * g0k, n1 = x1 * rs * g1k;
    bf16x2 o;
    o.x = (bf16_t)(rp.x * n0 + rp.y * n1);
    o.y = (bf16_t)(rp.z * n0 + rp.w * n1);
    *(bf16x2*)(k + base) = o;
  }
}

// ---------------------------------------------------------------- V transpose
__global__ __launch_bounds__(256)
void transpose_v(const bf16_t* __restrict__ v, bf16_t* __restrict__ vt) {
  __shared__ bf16_t st[64][68];
  const int t = threadIdx.x;
  const int bh = blockIdx.z;
  const int s0 = blockIdx.x * 64, d0 = blockIdx.y * 64;
  const bf16_t* vp = v + (size_t)bh * 2048 * 128;
  bf16_t* vtp = vt + (size_t)bh * 128 * 2048;
  const int r = t >> 4, c = (t & 15) * 4;
#pragma unroll
  for (int p = 0; p < 4; ++p) {
    bf16x4 x = *(const bf16x4*)(vp + (size_t)(s0 + r + p * 16) * 128 + d0 + c);
    *(bf16x4*)&st[r + p * 16][c] = x;
  }
  __syncthreads();
#pragma unroll
  for (int p = 0; p < 4; ++p) {
    int dr = r + p * 16;
    bf16x4 y;
    y.x = st[c + 0][dr]; y.y = st[c + 1][dr]; y.z = st[c + 2][dr]; y.w = st[c + 3][dr];
    *(bf16x4*)(vtp + (size_t)(d0 + dr) * 2048 + s0 + c) = y;
  }
}

// ---------------------------------------------------------------- flash attention
// 8 waves x 16 q-rows (512 thr). K/V staged in LDS (KVBLK=64, dbuf, swizzled
// via pre-swizzled source). P stays in registers: cvt_pk_bf16 pairs +
// v_permlane32_swap + v_permlane16_swap land the exact PV A-fragment.
// Defer-rescale (THR=8 in log2 domain). LDS 64KB -> 2 blocks/CU, 16 waves/CU.
__global__ __launch_bounds__(512, 4)
void attn_fwd(const bf16_t* __restrict__ Q, const bf16_t* __restrict__ K,
              const bf16_t* __restrict__ VT, bf16_t* __restrict__ O) {
  __shared__ __align__(16) char smem[65536];  // K0,K1 @0/16384; V0,V1 @32768/49152
  const int t = threadIdx.x, l = t & 63, wv = t >> 6;
  const int lq = l & 15, grp = l >> 4;
  const int bid = blockIdx.x;
  const int xcd = bid & 7, ksid = bid >> 3;
  const int bh = ((ksid >> 4) << 3) | xcd;   // 4 bh per XCD -> K/V fits L2
  const int qbi = ksid & 15;
  const int b_ = bh >> 4, h = bh & 15;
  const bf16_t* Qp = Q + (size_t)bh * 2048 * 128;
  const bf16_t* Kp = K + (size_t)bh * 2048 * 128;
  const bf16_t* Vp = VT + (size_t)bh * 128 * 2048;
  const int q0 = qbi * 128 + wv * 16;
  const int axor = lq & 7;

  // staging offsets: 2 K-granules + 2 V-granules per thread (1024 slots each)
  int ksoff[2], vsoff[2], dstoff[2];
#pragma unroll
  for (int i = 0; i < 2; ++i) {
    int g = i * 512 + t;
    int kr = g >> 4, kc = g & 15;              // K tile: 64 rows x 16 granules
    ksoff[i] = kr * 256 + ((kc ^ (kr & 7)) << 4);
    int vr = g >> 3, vc = g & 7;               // V tile: 128 rows x 8 granules
    vsoff[i] = vr * 4096 + ((vc ^ (vr & 7)) << 4);
    dstoff[i] = i * 8192 + wv * 1024;          // wave-uniform dst base
  }

  bf16x8 qf[4];
#pragma unroll
  for (int c = 0; c < 4; ++c)
    qf[c] = *(const bf16x8*)(Qp + (size_t)(q0 + lq) * 128 + c * 32 + grp * 8);

  f32x4 o[8];
  const f32x4 zf = {0.f, 0.f, 0.f, 0.f};
#pragma unroll
  for (int d = 0; d < 8; ++d) o[d] = zf;
  float m_run = -1e30f, l_run = 0.f;

  auto stage = [&](int buf, int kvb) {
    char* kdst = smem + buf * 16384;
    char* vdst = smem + 32768 + buf * 16384;
    const char* ksrc = (const char*)Kp + (size_t)kvb * 256;
    const char* vsrc = (const char*)Vp + (size_t)kvb * 2;
#pragma unroll
    for (int i = 0; i < 2; ++i) load_lds16(ksrc + ksoff[i], kdst + dstoff[i]);
#pragma unroll
    for (int i = 0; i < 2; ++i) load_lds16(vsrc + vsoff[i], vdst + dstoff[i]);
  };

  stage(0, 0);
  __syncthreads();

  for (int it = 0; it < 32; ++it) {
    const int cur = it & 1;
    if (it < 31) stage(cur ^ 1, (it + 1) * 64);
    const char* kb = smem + cur * 16384;
    const char* vb = smem + 32768 + cur * 16384;

    // ---- QK^T: lane holds S^T[kv=kvt*16+grp*4+r][q=lq]
    f32x4 sc[4];
#pragma unroll
    for (int kvt = 0; kvt < 4; ++kvt) sc[kvt] = zf;
    __builtin_amdgcn_s_setprio(1);
#pragma unroll
    for (int kvt = 0; kvt < 4; ++kvt)
#pragma unroll
      for (int c = 0; c < 4; ++c) {
        bf16x8 kf = *(const bf16x8*)(kb + (kvt * 16 + lq) * 256 +
                                     ((((c << 2) + grp) ^ axor) << 4));
        sc[kvt] = __builtin_amdgcn_mfma_f32_16x16x32_bf16(kf, qf[c], sc[kvt], 0, 0, 0);
      }
    __builtin_amdgcn_s_setprio(0);

    // ---- online softmax (log2 domain), defer-rescale THR=8
    float tm = fmaxf(fmaxf(fmaxf(fmaxf(sc[0][0], sc[0][1]), fmaxf(sc[0][2], sc[0][3])),
                           fmaxf(fmaxf(sc[1][0], sc[1][1]), fmaxf(sc[1][2], sc[1][3]))),
                     fmaxf(fmaxf(fmaxf(sc[2][0], sc[2][1]), fmaxf(sc[2][2], sc[2][3])),
                           fmaxf(fmaxf(sc[3][0], sc[3][1]), fmaxf(sc[3][2], sc[3][3]))));
    tm = fmaxf(tm, __shfl_xor(tm, 16));
    tm = fmaxf(tm, __shfl_xor(tm, 32));
    if (!__all(tm <= m_run + 8.0f)) {
      float mnew = fmaxf(m_run, tm);
      float alpha = __builtin_amdgcn_exp2f(m_run - mnew);
      m_run = mnew;
      l_run *= alpha;
      float ar0 = __shfl(alpha, (l & 48) | (grp * 4 + 0));
      float ar1 = __shfl(alpha, (l & 48) | (grp * 4 + 1));
      float ar2 = __shfl(alpha, (l & 48) | (grp * 4 + 2));
      float ar3 = __shfl(alpha, (l & 48) | (grp * 4 + 3));
#pragma unroll
      for (int dc = 0; dc < 8; ++dc) {
        o[dc][0] *= ar0; o[dc][1] *= ar1;
        o[dc][2] *= ar2; o[dc][3] *= ar3;
      }
    }
    float p[4][4];
    float ts = 0.f;
#pragma unroll
    for (int kvt = 0; kvt < 4; ++kvt) {
      p[kvt][0] = __builtin_amdgcn_exp2f(sc[kvt][0] - m_run);
      p[kvt][1] = __builtin_amdgcn_exp2f(sc[kvt][1] - m_run);
      p[kvt][2] = __builtin_amdgcn_exp2f(sc[kvt][2] - m_run);
      p[kvt][3] = __builtin_amdgcn_exp2f(sc[kvt][3] - m_run);
      ts += (p[kvt][0] + p[kvt][1]) + (p[kvt][2] + p[kvt][3]);
    }
    ts += __shfl_xor(ts, 16);
    ts += __shfl_xor(ts, 32);
    l_run += ts;

    // ---- pack P to bf16 pairs: w[kvt][h] = (p[kvt][2h], p[kvt][2h+1])
    unsigned w_[4][2];
#pragma unroll
    for (int kvt = 0; kvt < 4; ++kvt) {
      asm("v_cvt_pk_bf16_f32 %0, %1, %2" : "=v"(w_[kvt][0]) : "v"(p[kvt][0]), "v"(p[kvt][1]));
      asm("v_cvt_pk_bf16_f32 %0, %1, %2" : "=v"(w_[kvt][1]) : "v"(p[kvt][2]), "v"(p[kvt][3]));
    }
    // ---- redistribute to PV A-fragment: lane(lq,g) gets P[lq][g*8+j] (+32*ks)
    union { unsigned u[4]; bf16x8 v; } pa[2];
#pragma unroll
    for (int ks = 0; ks < 2; ++ks)
#pragma unroll
      for (int hh = 0; hh < 2; ++hh) {
        unsigned a = w_[2 * ks][hh], b = w_[2 * ks + 1][hh];
        asm volatile("v_permlane32_swap_b32 %0, %1" : "+v"(a), "+v"(b));
        asm volatile("v_permlane16_swap_b32 %0, %1" : "+v"(a), "+v"(b));
        pa[ks].u[hh] = a; pa[ks].u[2 + hh] = b;
      }

    // ---- PV
    __builtin_amdgcn_s_setprio(1);
#pragma unroll
    for (int dc = 0; dc < 8; ++dc)
#pragma unroll
      for (int ks = 0; ks < 2; ++ks) {
        bf16x8 vf = *(const bf16x8*)(vb + (dc * 16 + lq) * 128 +
                                     ((((ks << 2) + grp) ^ axor) << 4));
        o[dc] = __builtin_amdgcn_mfma_f32_16x16x32_bf16(pa[ks].v, vf, o[dc], 0, 0, 0);
      }
    __builtin_amdgcn_s_setprio(0);
    __syncthreads();   // stage(it+1) landed + all waves done with buf[cur]
  }

  float i0 = 1.f / __shfl(l_run, (l & 48) | (grp * 4 + 0));
  float i1 = 1.f / __shfl(l_run, (l & 48) | (grp * 4 + 1));
  float i2 = 1.f / __shfl(l_run, (l & 48) | (grp * 4 + 2));
  float i3 = 1.f / __shfl(l_run, (l & 48) | (grp * 4 + 3));
#pragma unroll
  for (int dc = 0; dc < 8; ++dc) {
    int d = dc * 16 + lq;
    int sg = q0 + grp * 4;
    O[(((size_t)b_ * 2048 + sg + 0) * 16 + h) * 128 + d] = (bf16_t)(o[dc][0] * i0);
    O[(((size_t)b_ * 2048 + sg + 1) * 16 + h) * 128 + d] = (bf16_t)(o[dc][1] * i1);
    O[(((size_t)b_ * 2048 + sg + 2) * 16 + h) * 128 + d] = (bf16_t)(o[dc][2] * i2);
    O[(((size_t)b_ * 2048 + sg + 3) * 16 + h) * 128 + d] = (bf16_t)(o[dc][3] * i3);
  }
}

// ---------------------------------------------------------------- launcher
extern "C" void kernel_launch(void* const* d_in, const int* in_sizes, int n_in,
                              void* d_out, int out_size, void* d_ws, size_t ws_size,
                              hipStream_t stream) {
  const float* x    = (const float*)d_in[0];
  const float* rope = (const float*)d_in[1];
  const float* Wq   = (const float*)d_in[2];
  const float* bq   = (const float*)d_in[3];
  const float* Wk   = (const float*)d_in[4];
  const float* bk   = (const float*)d_in[5];
  const float* Wv   = (const float*)d_in[6];
  const float* bv   = (const float*)d_in[7];
  const float* gq   = (const float*)d_in[8];
  const float* gk   = (const float*)d_in[9];
  const float* Wo   = (const float*)d_in[10];
  const float* bo   = (const float*)d_in[11];
  float* out = (float*)d_out;
  char* ws = (char*)d_ws;

  bf16_t* xbf  = (bf16_t*)(ws);
  bf16_t* wqkv = (bf16_t*)(ws + 16777216);
  bf16_t* wobf = (bf16_t*)(ws + 41943040);
  bf16_t* qb   = (bf16_t*)(ws + 50331648);
  bf16_t* kb   = (bf16_t*)(ws + 67108864);
  bf16_t* vb   = (bf16_t*)(ws + 83886080);
  bf16_t* vtb  = (bf16_t*)(ws);              // alias xbf (dead after GEMM1)
  bf16_t* aob  = (bf16_t*)(ws + 16777216);   // alias wqkv

  cast_all<<<2048, 256, 0, stream>>>((const float4*)x, (const float4*)Wq,
                                     (const float4*)Wk, (const float4*)Wv,
                                     (const float4*)Wo,
                                     (bf16x4*)xbf, (bf16x4*)wqkv, (bf16x4*)wobf);

  gemm_bt<0><<<dim3(48, 32), 256, 0, stream>>>(xbf, wqkv, 4096, 6144, 2048,
                                               bq, bk, bv, nullptr, qb, kb, vb);
  normrope<<<16384, 256, 0, stream>>>(qb, kb, rope, gq, gk);
  transpose_v<<<dim3(32, 2, 32), 256, 0, stream>>>(vb, vtb);
  attn_fwd<<<512, 512, 0, stream>>>(qb, kb, vtb, aob);
  gemm_bt<1><<<dim3(16, 32), 256, 0, stream>>>(aob, wobf, 4096, 2048, 2048,
                                               bo, nullptr, nullptr, out,
                                               nullptr, nullptr, nullptr);
}